// Round 11
// baseline (332.124 us; speedup 1.0000x reference)
//
#include <hip/hip_runtime.h>

// Problem constants
#define N_TOK 2304
#define CDIM  1280
#define NH    8
#define DH    160
#define NKT   36          // N_TOK / 64  (u64 bitmask words per row)
#define SCALE 0.07905694150420949f   // 1/sqrt(160)
#define LOG2E 1.4426950408889634f

// Fragment-major buffer geometry (bytes)
#define FRAG_BH   737280     // 160*2304*2 per (b,h)
#define KCH_STR   10240      // 10 ks-chunks of 1KB per 32-key (or 32-q) tile
#define VCH_STR   5120       // 5 dt-chunks of 1KB per 16-key step

typedef __attribute__((ext_vector_type(8))) short bf16x8;
typedef __attribute__((ext_vector_type(4))) float f32x4;
typedef __attribute__((ext_vector_type(16))) float f32x16;

#define MFMA16(a, b, c) __builtin_amdgcn_mfma_f32_16x16x32_bf16((a), (b), (c), 0, 0, 0)
#define MFMA32(a, b, c) __builtin_amdgcn_mfma_f32_32x32x16_bf16((a), (b), (c), 0, 0, 0)

static __device__ __forceinline__ unsigned short f2bf(float f) {
  // round-to-nearest-even f32 -> bf16 (finite inputs only)
  unsigned int u = __builtin_bit_cast(unsigned int, f);
  u += 0x7fffu + ((u >> 16) & 1u);
  return (unsigned short)(u >> 16);
}

static __device__ __forceinline__ float fexp2(float x) {
#if __has_builtin(__builtin_amdgcn_exp2f)
  return __builtin_amdgcn_exp2f(x);
#else
  return exp2f(x);
#endif
}

// global -> LDS direct DMA, 16B per lane. LDS dest = wave-uniform base + lane*16.
static __device__ __forceinline__ void gload_lds16(const void* g, void* l) {
  const __attribute__((address_space(1))) unsigned int* gp =
      (const __attribute__((address_space(1))) unsigned int*)(unsigned long long)(uintptr_t)g;
  __attribute__((address_space(3))) unsigned int* lp =
      (__attribute__((address_space(3))) unsigned int*)(unsigned int)(uintptr_t)l;
  __builtin_amdgcn_global_load_lds(gp, lp, 16, 0, 0);
}

// ---------------- fused prep kernel ----------------
// Section A [0,2880): cast hidden_states f32 -> bf16 (8 elems/thread)
// Section B [2880,7680): Wt[w][n][k] = W_w[k][n] f32 -> bf16 (32x32 LDS tiles)
// Section C [7680,49152): masks -> fragment-blocked visibility bits
__global__ void prep_fused_kernel(const float* __restrict__ x,
                                  const float* __restrict__ wq,
                                  const float* __restrict__ wk,
                                  const float* __restrict__ wv,
                                  const float* __restrict__ masks,
                                  unsigned short* __restrict__ xbf,
                                  unsigned short* __restrict__ wt,
                                  unsigned int* __restrict__ bitsF) {
  const int blk = blockIdx.x;
  const int tid = threadIdx.x;
  if (blk < 2880) {
    int i = blk * 256 + tid;
    const float4* p = (const float4*)x + (size_t)i * 2;
    float4 a = p[0], b = p[1];
    union { unsigned short u[8]; uint4 v; } pk;
    pk.u[0] = f2bf(a.x); pk.u[1] = f2bf(a.y); pk.u[2] = f2bf(a.z); pk.u[3] = f2bf(a.w);
    pk.u[4] = f2bf(b.x); pk.u[5] = f2bf(b.y); pk.u[6] = f2bf(b.z); pk.u[7] = f2bf(b.w);
    ((uint4*)xbf)[i] = pk.v;
  } else if (blk < 7680) {
    __shared__ float t[32][33];
    int idx = blk - 2880;
    int w = idx / 1600, r = idx - w * 1600;
    const float* src = (w == 0) ? wq : ((w == 1) ? wk : wv);
    int bx = (r % 40) * 32, by = (r / 40) * 32;
    int tx = tid & 31, ty = tid >> 5;     // 32 x 8
#pragma unroll
    for (int i = 0; i < 32; i += 8)
      t[ty + i][tx] = src[(size_t)(by + ty + i) * CDIM + bx + tx];
    __syncthreads();
#pragma unroll
    for (int i = 0; i < 32; i += 8)
      wt[((size_t)w * CDIM + bx + ty + i) * CDIM + by + tx] = f2bf(t[tx][ty + i]);
  } else {
    int tt = (blk - 7680) * 256 + tid;
    int word = tt >> 6, lane = tt & 63;
    int jblk = word % NKT, bi = word / NKT;          // bi = b*N + i
    float m = masks[(size_t)bi * N_TOK + jblk * 64 + lane];
    unsigned long long vis = __ballot(m > -5000.0f);
    int b = bi / N_TOK, i = bi - b * N_TOK;
    int qt = i >> 5, ql = i & 31;
    unsigned base = ((unsigned)(b * 72 + qt) * 72 + 2 * jblk) * 32 + ql;
    if (lane == 0)      bitsF[base]      = (unsigned)vis;
    else if (lane == 1) bitsF[base + 32] = (unsigned)(vis >> 32);
  }
}

// ---------------- QKV projection GEMM (unchanged, verified) ----------------
__global__ __launch_bounds__(256, 3) void gemm_qkv_kernel(
    const unsigned short* __restrict__ xbf, const unsigned short* __restrict__ wt,
    char* __restrict__ qfrag, char* __restrict__ kfrag, char* __restrict__ vfrag) {
  __shared__ unsigned short Al[128][64];   // 128B rows, linear (DMA dest)
  __shared__ unsigned short Bl[128][64];
  const int tid = threadIdx.x;
  const int lane = tid & 63, wv = tid >> 6;
  const int wm = wv >> 1, wn = wv & 1;
  const int l15 = lane & 15, l4 = lane >> 4;
  const int m0 = blockIdx.x * 128, n0 = blockIdx.y * 128;
  const int lr8 = lane >> 3;                       // 0..7: row within 8-row slab
  const int scb = ((lane & 7) * 16) ^ (lr8 << 4);  // pre-swizzled source column
  f32x4 zero = {0.f, 0.f, 0.f, 0.f};
  f32x4 acc[4][4];
#pragma unroll
  for (int mt = 0; mt < 4; mt++)
#pragma unroll
    for (int nt = 0; nt < 4; nt++) acc[mt][nt] = zero;

  for (int kk = 0; kk < CDIM; kk += 64) {
    __syncthreads();   // prior reads done before DMA overwrites
    {
      const char* asrc = (const char*)&xbf[(size_t)(m0 + wv * 32) * CDIM + kk];
      const char* bsrc = (const char*)&wt [(size_t)(n0 + wv * 32) * CDIM + kk];
#pragma unroll
      for (int i = 0; i < 4; i++) {
        gload_lds16(asrc + (size_t)(i * 8 + lr8) * (CDIM * 2) + scb, &Al[wv * 32 + i * 8][0]);
        gload_lds16(bsrc + (size_t)(i * 8 + lr8) * (CDIM * 2) + scb, &Bl[wv * 32 + i * 8][0]);
      }
    }
    __syncthreads();   // vmcnt(0) drain emitted before barrier
#pragma unroll
    for (int ks = 0; ks < 2; ks++) {
      bf16x8 af[4], bfr[4];
#pragma unroll
      for (int mt = 0; mt < 4; mt++) {
        int rA = wm * 64 + mt * 16 + l15;
        af[mt] = *(const bf16x8*)((const char*)Al + rA * 128 +
                                  ((ks * 64 + l4 * 16) ^ ((rA & 7) << 4)));
      }
#pragma unroll
      for (int nt = 0; nt < 4; nt++) {
        int rB = wn * 64 + nt * 16 + l15;
        bfr[nt] = *(const bf16x8*)((const char*)Bl + rB * 128 +
                                   ((ks * 64 + l4 * 16) ^ ((rB & 7) << 4)));
      }
#pragma unroll
      for (int mt = 0; mt < 4; mt++)
#pragma unroll
        for (int nt = 0; nt < 4; nt++)
          acc[mt][nt] = MFMA16(af[mt], bfr[nt], acc[mt][nt]);
    }
  }

  const int w_idx = n0 / CDIM;                 // 0=Q 1=K 2=V, block-uniform
  if (w_idx == 0) {
    const float qsc = (float)(0.07905694150420949 * 1.4426950408889634);
#pragma unroll
    for (int mt = 0; mt < 4; mt++)
#pragma unroll
      for (int nt = 0; nt < 4; nt++) acc[mt][nt] *= qsc;
  }
  const int cbase = n0 - w_idx * CDIM + wn * 64;
#pragma unroll
  for (int mt = 0; mt < 4; mt++) {
    const int mg = m0 + wm * 64 + mt * 16 + l4 * 4;  // token row (r=0)
    const int b = mg / N_TOK;
    const int tok = mg - b * N_TOK;
#pragma unroll
    for (int nt = 0; nt < 4; nt++) {
      const int cw = cbase + nt * 16 + l15;
      const int h = cw / DH, d = cw - h * DH;
      const size_t bh = (size_t)(b * NH + h);
      if (w_idx == 2) {
        union { unsigned short u[4]; unsigned long long v; } pk;
        pk.u[0] = f2bf(acc[mt][nt][0]); pk.u[1] = f2bf(acc[mt][nt][1]);
        pk.u[2] = f2bf(acc[mt][nt][2]); pk.u[3] = f2bf(acc[mt][nt][3]);
        char* p = vfrag + bh * FRAG_BH + (tok >> 4) * VCH_STR + (d >> 5) * 1024
                  + ((d & 31) + 32 * ((tok >> 3) & 1)) * 16 + (tok & 7) * 2;
        *(unsigned long long*)p = pk.v;
      } else {
        char* base = (w_idx == 0 ? qfrag : kfrag) + bh * FRAG_BH + (d >> 4) * 1024
                     + ((d >> 3) & 1) * 512 + (d & 7) * 2;
#pragma unroll
        for (int r = 0; r < 4; r++) {
          int t2 = tok + r;
          *(unsigned short*)(base + (t2 >> 5) * KCH_STR + (t2 & 31) * 16) =
              f2bf(acc[mt][nt][r]);
        }
      }
    }
  }
}

// ---------------- attention helpers (verified attn8 code, factored) --------

// online-softmax for one 32-key tile of one q-tile; consumes s, updates
// (run_m, run_l, o-rescale), emits the 8 packed-bf16 P words.
static __device__ __forceinline__ void softmax_block(
    const f32x16& s, unsigned mw, float& run_m, float& run_l,
    f32x16 (&o)[5], int h, unsigned (&pw)[8]) {
  float t0 = fmaxf(fmaxf(fmaxf(s[0], s[1]), fmaxf(s[2], s[3])),
                   fmaxf(fmaxf(s[4], s[5]), fmaxf(s[6], s[7])));
  float t1 = fmaxf(fmaxf(fmaxf(s[8], s[9]), fmaxf(s[10], s[11])),
                   fmaxf(fmaxf(s[12], s[13]), fmaxf(s[14], s[15])));
  float pm = fmaxf(t0, t1);
  pm = fmaxf(pm, __shfl_xor(pm, 32));

  // defer-max (T13): skip O-rescale unless max grew by > 8 (log2 units)
  if (!__all(pm - run_m <= 8.0f)) {
    float nm = fmaxf(run_m, pm);
    float f = fexp2(run_m - nm);
    run_m = nm;
    run_l *= f;
#pragma unroll
    for (int dt = 0; dt < 5; dt++) o[dt] *= f;
  }

  float rs = 0.0f;
#pragma unroll
  for (int i = 0; i < 8; i++) {
    int k0 = ((2 * i) & 3) + 8 * (i >> 1) + 4 * h;   // key of reg 2i
    float p0 = fexp2(s[2 * i] - run_m);
    float p1 = fexp2(s[2 * i + 1] - run_m);
    p0 = ((mw >> k0) & 1u) ? p0 : 0.0f;              // mask by zeroing P
    p1 = ((mw >> (k0 + 1)) & 1u) ? p1 : 0.0f;
    rs += p0 + p1;
    unsigned w;
    asm("v_cvt_pk_bf16_f32 %0, %1, %2" : "=v"(w) : "v"(p0), "v"(p1));
    pw[i] = w;
  }
  rs += __shfl_xor(rs, 32);
  run_l += rs;
}

// PV accumulate: P-frag assembly via permlane32_swap, then 2x5 MFMA.
static __device__ __forceinline__ void pv_block(
    const unsigned (&pw)[8], const bf16x8 (&va)[5], const bf16x8 (&vb_)[5],
    f32x16 (&o)[5]) {
  unsigned a1 = pw[0], b1 = pw[2];
  asm("v_permlane32_swap_b32 %0, %1" : "+v"(a1), "+v"(b1));
  unsigned a2 = pw[1], b2 = pw[3];
  asm("v_permlane32_swap_b32 %0, %1" : "+v"(a2), "+v"(b2));
  union { unsigned w[4]; bf16x8 v; } u;
  u.w[0] = a1; u.w[1] = a2; u.w[2] = b1; u.w[3] = b2;
  __builtin_amdgcn_s_setprio(1);
#pragma unroll
  for (int dt = 0; dt < 5; dt++) o[dt] = MFMA32(va[dt], u.v, o[dt]);
  __builtin_amdgcn_s_setprio(0);
  unsigned c1 = pw[4], d1 = pw[6];
  asm("v_permlane32_swap_b32 %0, %1" : "+v"(c1), "+v"(d1));
  unsigned c2 = pw[5], d2 = pw[7];
  asm("v_permlane32_swap_b32 %0, %1" : "+v"(c2), "+v"(d2));
  union { unsigned w[4]; bf16x8 v; } u2;
  u2.w[0] = c1; u2.w[1] = c2; u2.w[2] = d1; u2.w[3] = d2;
  __builtin_amdgcn_s_setprio(1);
#pragma unroll
  for (int dt = 0; dt < 5; dt++) o[dt] = MFMA32(vb_[dt], u2.v, o[dt]);
  __builtin_amdgcn_s_setprio(0);
}

// ---------------- fused masked flash attention v10 ----------------
// 1-wave blocks, 64 q-rows per wave (two q-tiles qf0/qf1, o0/o1): the SAME
// 20.5 KB/iter of K/V now feeds 40 MFMA -> total loop read traffic halves
// (attacks the measured 15 TB/s aggregate wall) with ZERO barriers and no
// inter-wave coupling (attn9's failure mode). ~390 VGPR -> 1 wave/SIMD tier;
// 576 blocks = 2.25/CU, one dispatch round.
__global__ __launch_bounds__(64, 1) void attn10_kernel(
    const char* __restrict__ qfrag, const char* __restrict__ kfrag,
    const char* __restrict__ vfrag, const unsigned int* __restrict__ bitsF,
    float* __restrict__ out) {
  __shared__ __align__(16) char smem[20480];   // epilogue transpose (per tile)
  const int lane = threadIdx.x & 63;
  const int l31 = lane & 31, h = lane >> 5;
  const int lane16 = lane * 16;
  const int id = blockIdx.x;
  const int rem = (id & 7) * 72 + (id >> 3);   // XCD-chunked remap (576 = 8*72)
  const int bh = rem / 36, qq = rem - (rem / 36) * 36;
  const int b = bh >> 3;
  const int qt0 = qq * 2;                      // two consecutive 32-row q-tiles

  const char* qfb0 = qfrag + (size_t)bh * FRAG_BH + (size_t)qt0 * KCH_STR;
  const char* kfb = kfrag + (size_t)bh * FRAG_BH;
  const char* vfb = vfrag + (size_t)bh * FRAG_BH;
  const unsigned int* bb0 = bitsF + (size_t)(b * 72 + qt0) * 72 * 32 + l31;
  const unsigned int* bb1 = bb0 + 72 * 32;

  // Q fragments for both tiles (pre-scaled by SCALE*LOG2E)
  bf16x8 qf0[10], qf1[10];
#pragma unroll
  for (int ks = 0; ks < 10; ks++) {
    qf0[ks] = *(const bf16x8*)(qfb0 + ks * 1024 + lane16);
    qf1[ks] = *(const bf16x8*)(qfb0 + KCH_STR + ks * 1024 + lane16);
  }

  const f32x16 zz = {0.f,0.f,0.f,0.f,0.f,0.f,0.f,0.f,0.f,0.f,0.f,0.f,0.f,0.f,0.f,0.f};
  f32x16 o0[5], o1[5];
#pragma unroll
  for (int dt = 0; dt < 5; dt++) { o0[dt] = zz; o1[dt] = zz; }
  float m0 = -3.0e38f, l0 = 0.0f, m1 = -3.0e38f, l1 = 0.0f;

  bf16x8 kf[10];
#pragma unroll
  for (int ks = 0; ks < 10; ks++) kf[ks] = *(const bf16x8*)(kfb + ks * 1024 + lane16);

  for (int kt = 0; kt < 72; kt++) {
    unsigned mw0 = bb0[kt * 32];
    unsigned mw1 = bb1[kt * 32];

    // V fragments for this tile: issued first (cover = 2x QK^T + softmax0)
    const char* vch = vfb + (size_t)kt * KCH_STR;
    bf16x8 va[5], vb_[5];
#pragma unroll
    for (int dt = 0; dt < 5; dt++) va[dt] = *(const bf16x8*)(vch + dt * 1024 + lane16);
#pragma unroll
    for (int dt = 0; dt < 5; dt++)
      vb_[dt] = *(const bf16x8*)(vch + 5120 + dt * 1024 + lane16);

    // S^T for both q-tiles (independent chains, shared kf)
    f32x16 s0 = zz, s1 = zz;
    __builtin_amdgcn_s_setprio(1);
#pragma unroll
    for (int ks = 0; ks < 10; ks++) s0 = MFMA32(kf[ks], qf0[ks], s0);
#pragma unroll
    for (int ks = 0; ks < 10; ks++) s1 = MFMA32(kf[ks], qf1[ks], s1);
    __builtin_amdgcn_s_setprio(0);

    // prefetch next K tile (after both QK^T consumed kf; cover = softmax+PV)
    if (kt + 1 < 72) {
      const char* kr = kfb + (size_t)(kt + 1) * KCH_STR;
#pragma unroll
      for (int ks = 0; ks < 10; ks++) kf[ks] = *(const bf16x8*)(kr + ks * 1024 + lane16);
    }

    unsigned pw0[8], pw1[8];
    softmax_block(s0, mw0, m0, l0, o0, h, pw0);
    pv_block(pw0, va, vb_, o0);                 // softmax1 VALU overlaps these MFMAs
    softmax_block(s1, mw1, m1, l1, o1, h, pw1);
    pv_block(pw1, va, vb_, o1);
  }

  // ---- epilogue: two tiles sequentially through the 20KB LDS transpose ----
  auto store_tile = [&](const f32x16 (&o)[5], float run_l, int q0v) {
    float invl = 1.0f / run_l;
#pragma unroll
    for (int dt = 0; dt < 5; dt++)
#pragma unroll
      for (int rr = 0; rr < 4; rr++) {
        float4 t;
        t.x = o[dt][4 * rr + 0] * invl;
        t.y = o[dt][4 * rr + 1] * invl;
        t.z = o[dt][4 * rr + 2] * invl;
        t.w = o[dt][4 * rr + 3] * invl;
        int d0 = dt * 32 + 8 * rr + 4 * h;
        *(float4*)(smem + l31 * 640 + ((d0 * 4) ^ ((l31 & 7) << 4))) = t;
      }
    __syncthreads();
    float* outp = out + ((size_t)b * N_TOK + q0v) * CDIM + (bh & 7) * DH;
#pragma unroll
    for (int i = 0; i < 20; i++) {
      int c = i * 64 + lane;
      int q = c / 40, f = c - (c / 40) * 40;
      float4 t = *(const float4*)(smem + q * 640 + ((f * 16) ^ ((q & 7) << 4)));
      *(float4*)&outp[(size_t)q * CDIM + f * 4] = t;
    }
    __syncthreads();   // before LDS reuse by the next tile
  };
  store_tile(o0, l0, qt0 * 32);
  store_tile(o1, l1, qt0 * 32 + 32);
}

// ---------------- launcher ----------------
extern "C" void kernel_launch(void* const* d_in, const int* in_sizes, int n_in,
                              void* d_out, int out_size, void* d_ws, size_t ws_size,
                              hipStream_t stream) {
  const float* hs    = (const float*)d_in[0];
  const float* wq    = (const float*)d_in[1];
  const float* wk    = (const float*)d_in[2];
  const float* wvw   = (const float*)d_in[3];
  const float* masks = (const float*)d_in[4];
  float* out = (float*)d_out;

  char* ws = (char*)d_ws;
  unsigned short* xbf = (unsigned short*)(ws);                    // 11,796,480 B
  unsigned short* wt  = (unsigned short*)(ws + 11796480);         //  9,830,400 B
  char* qf = ws + 21626880;                                       // 11,796,480 B
  char* kf = ws + 33423360;                                       // 11,796,480 B
  char* vf = ws + 45219840;                                       // 11,796,480 B
  unsigned int* bitsF = (unsigned int*)(ws + 57016320);           //  1,327,104 B
  // total workspace: 58,343,424 B

  prep_fused_kernel<<<49152, 256, 0, stream>>>(hs, wq, wk, wvw, masks, xbf, wt, bitsF);
  gemm_qkv_kernel<<<dim3(36, 30), 256, 0, stream>>>(xbf, wt, qf, kf, vf);
  attn10_kernel<<<576, 64, 0, stream>>>(qf, kf, vf, bitsF, out);
}

// Round 12
// 325.831 us; speedup vs baseline: 1.0193x; 1.0193x over previous
//
#include <hip/hip_runtime.h>

// Problem constants
#define N_TOK 2304
#define CDIM  1280
#define NH    8
#define DH    160
#define NKT   36          // N_TOK / 64  (u64 bitmask words per row)
#define SCALE 0.07905694150420949f   // 1/sqrt(160)
#define LOG2E 1.4426950408889634f

// Fragment-major buffer geometry (bytes)
#define FRAG_BH   737280     // 160*2304*2 per (b,h)
#define KCH_STR   10240      // 10 ks-chunks of 1KB per 32-key (or 32-q) tile
#define VCH_STR   5120       // 5 dt-chunks of 1KB per 16-key step

typedef __attribute__((ext_vector_type(8))) short bf16x8;
typedef __attribute__((ext_vector_type(4))) float f32x4;
typedef __attribute__((ext_vector_type(16))) float f32x16;

#define MFMA16(a, b, c) __builtin_amdgcn_mfma_f32_16x16x32_bf16((a), (b), (c), 0, 0, 0)
#define MFMA32(a, b, c) __builtin_amdgcn_mfma_f32_32x32x16_bf16((a), (b), (c), 0, 0, 0)

// PV MFMA with accumulator PINNED to AGPRs ("a" constraint): keeps the two
// 80-reg O accumulators out of the 256-entry arch-VGPR file (attn10's spill).
static __device__ __forceinline__ void mfma_a(f32x16& acc, const bf16x8& a,
                                              const bf16x8& b) {
  asm("v_mfma_f32_32x32x16_bf16 %0, %1, %2, %0" : "+a"(acc) : "v"(a), "v"(b));
}

static __device__ __forceinline__ unsigned short f2bf(float f) {
  // round-to-nearest-even f32 -> bf16 (finite inputs only)
  unsigned int u = __builtin_bit_cast(unsigned int, f);
  u += 0x7fffu + ((u >> 16) & 1u);
  return (unsigned short)(u >> 16);
}

static __device__ __forceinline__ float fexp2(float x) {
#if __has_builtin(__builtin_amdgcn_exp2f)
  return __builtin_amdgcn_exp2f(x);
#else
  return exp2f(x);
#endif
}

// global -> LDS direct DMA, 16B per lane. LDS dest = wave-uniform base + lane*16.
static __device__ __forceinline__ void gload_lds16(const void* g, void* l) {
  const __attribute__((address_space(1))) unsigned int* gp =
      (const __attribute__((address_space(1))) unsigned int*)(unsigned long long)(uintptr_t)g;
  __attribute__((address_space(3))) unsigned int* lp =
      (__attribute__((address_space(3))) unsigned int*)(unsigned int)(uintptr_t)l;
  __builtin_amdgcn_global_load_lds(gp, lp, 16, 0, 0);
}

// ---------------- fused prep kernel ----------------
// Section A [0,2880): cast hidden_states f32 -> bf16 (8 elems/thread)
// Section B [2880,7680): Wt[w][n][k] = W_w[k][n] f32 -> bf16 (32x32 LDS tiles)
// Section C [7680,49152): masks -> fragment-blocked visibility bits
__global__ void prep_fused_kernel(const float* __restrict__ x,
                                  const float* __restrict__ wq,
                                  const float* __restrict__ wk,
                                  const float* __restrict__ wv,
                                  const float* __restrict__ masks,
                                  unsigned short* __restrict__ xbf,
                                  unsigned short* __restrict__ wt,
                                  unsigned int* __restrict__ bitsF) {
  const int blk = blockIdx.x;
  const int tid = threadIdx.x;
  if (blk < 2880) {
    int i = blk * 256 + tid;
    const float4* p = (const float4*)x + (size_t)i * 2;
    float4 a = p[0], b = p[1];
    union { unsigned short u[8]; uint4 v; } pk;
    pk.u[0] = f2bf(a.x); pk.u[1] = f2bf(a.y); pk.u[2] = f2bf(a.z); pk.u[3] = f2bf(a.w);
    pk.u[4] = f2bf(b.x); pk.u[5] = f2bf(b.y); pk.u[6] = f2bf(b.z); pk.u[7] = f2bf(b.w);
    ((uint4*)xbf)[i] = pk.v;
  } else if (blk < 7680) {
    __shared__ float t[32][33];
    int idx = blk - 2880;
    int w = idx / 1600, r = idx - w * 1600;
    const float* src = (w == 0) ? wq : ((w == 1) ? wk : wv);
    int bx = (r % 40) * 32, by = (r / 40) * 32;
    int tx = tid & 31, ty = tid >> 5;     // 32 x 8
#pragma unroll
    for (int i = 0; i < 32; i += 8)
      t[ty + i][tx] = src[(size_t)(by + ty + i) * CDIM + bx + tx];
    __syncthreads();
#pragma unroll
    for (int i = 0; i < 32; i += 8)
      wt[((size_t)w * CDIM + bx + ty + i) * CDIM + by + tx] = f2bf(t[tx][ty + i]);
  } else {
    int tt = (blk - 7680) * 256 + tid;
    int word = tt >> 6, lane = tt & 63;
    int jblk = word % NKT, bi = word / NKT;          // bi = b*N + i
    float m = masks[(size_t)bi * N_TOK + jblk * 64 + lane];
    unsigned long long vis = __ballot(m > -5000.0f);
    int b = bi / N_TOK, i = bi - b * N_TOK;
    int qt = i >> 5, ql = i & 31;
    unsigned base = ((unsigned)(b * 72 + qt) * 72 + 2 * jblk) * 32 + ql;
    if (lane == 0)      bitsF[base]      = (unsigned)vis;
    else if (lane == 1) bitsF[base + 32] = (unsigned)(vis >> 32);
  }
}

// ---------------- QKV projection GEMM (unchanged, verified) ----------------
__global__ __launch_bounds__(256, 3) void gemm_qkv_kernel(
    const unsigned short* __restrict__ xbf, const unsigned short* __restrict__ wt,
    char* __restrict__ qfrag, char* __restrict__ kfrag, char* __restrict__ vfrag) {
  __shared__ unsigned short Al[128][64];   // 128B rows, linear (DMA dest)
  __shared__ unsigned short Bl[128][64];
  const int tid = threadIdx.x;
  const int lane = tid & 63, wv = tid >> 6;
  const int wm = wv >> 1, wn = wv & 1;
  const int l15 = lane & 15, l4 = lane >> 4;
  const int m0 = blockIdx.x * 128, n0 = blockIdx.y * 128;
  const int lr8 = lane >> 3;                       // 0..7: row within 8-row slab
  const int scb = ((lane & 7) * 16) ^ (lr8 << 4);  // pre-swizzled source column
  f32x4 zero = {0.f, 0.f, 0.f, 0.f};
  f32x4 acc[4][4];
#pragma unroll
  for (int mt = 0; mt < 4; mt++)
#pragma unroll
    for (int nt = 0; nt < 4; nt++) acc[mt][nt] = zero;

  for (int kk = 0; kk < CDIM; kk += 64) {
    __syncthreads();   // prior reads done before DMA overwrites
    {
      const char* asrc = (const char*)&xbf[(size_t)(m0 + wv * 32) * CDIM + kk];
      const char* bsrc = (const char*)&wt [(size_t)(n0 + wv * 32) * CDIM + kk];
#pragma unroll
      for (int i = 0; i < 4; i++) {
        gload_lds16(asrc + (size_t)(i * 8 + lr8) * (CDIM * 2) + scb, &Al[wv * 32 + i * 8][0]);
        gload_lds16(bsrc + (size_t)(i * 8 + lr8) * (CDIM * 2) + scb, &Bl[wv * 32 + i * 8][0]);
      }
    }
    __syncthreads();   // vmcnt(0) drain emitted before barrier
#pragma unroll
    for (int ks = 0; ks < 2; ks++) {
      bf16x8 af[4], bfr[4];
#pragma unroll
      for (int mt = 0; mt < 4; mt++) {
        int rA = wm * 64 + mt * 16 + l15;
        af[mt] = *(const bf16x8*)((const char*)Al + rA * 128 +
                                  ((ks * 64 + l4 * 16) ^ ((rA & 7) << 4)));
      }
#pragma unroll
      for (int nt = 0; nt < 4; nt++) {
        int rB = wn * 64 + nt * 16 + l15;
        bfr[nt] = *(const bf16x8*)((const char*)Bl + rB * 128 +
                                   ((ks * 64 + l4 * 16) ^ ((rB & 7) << 4)));
      }
#pragma unroll
      for (int mt = 0; mt < 4; mt++)
#pragma unroll
        for (int nt = 0; nt < 4; nt++)
          acc[mt][nt] = MFMA16(af[mt], bfr[nt], acc[mt][nt]);
    }
  }

  const int w_idx = n0 / CDIM;                 // 0=Q 1=K 2=V, block-uniform
  if (w_idx == 0) {
    const float qsc = (float)(0.07905694150420949 * 1.4426950408889634);
#pragma unroll
    for (int mt = 0; mt < 4; mt++)
#pragma unroll
      for (int nt = 0; nt < 4; nt++) acc[mt][nt] *= qsc;
  }
  const int cbase = n0 - w_idx * CDIM + wn * 64;
#pragma unroll
  for (int mt = 0; mt < 4; mt++) {
    const int mg = m0 + wm * 64 + mt * 16 + l4 * 4;  // token row (r=0)
    const int b = mg / N_TOK;
    const int tok = mg - b * N_TOK;
#pragma unroll
    for (int nt = 0; nt < 4; nt++) {
      const int cw = cbase + nt * 16 + l15;
      const int h = cw / DH, d = cw - h * DH;
      const size_t bh = (size_t)(b * NH + h);
      if (w_idx == 2) {
        union { unsigned short u[4]; unsigned long long v; } pk;
        pk.u[0] = f2bf(acc[mt][nt][0]); pk.u[1] = f2bf(acc[mt][nt][1]);
        pk.u[2] = f2bf(acc[mt][nt][2]); pk.u[3] = f2bf(acc[mt][nt][3]);
        char* p = vfrag + bh * FRAG_BH + (tok >> 4) * VCH_STR + (d >> 5) * 1024
                  + ((d & 31) + 32 * ((tok >> 3) & 1)) * 16 + (tok & 7) * 2;
        *(unsigned long long*)p = pk.v;
      } else {
        char* base = (w_idx == 0 ? qfrag : kfrag) + bh * FRAG_BH + (d >> 4) * 1024
                     + ((d >> 3) & 1) * 512 + (d & 7) * 2;
#pragma unroll
        for (int r = 0; r < 4; r++) {
          int t2 = tok + r;
          *(unsigned short*)(base + (t2 >> 5) * KCH_STR + (t2 & 31) * 16) =
              f2bf(acc[mt][nt][r]);
        }
      }
    }
  }
}

// ---------------- attention helpers (verified attn10 code) --------

// online-softmax for one 32-key tile of one q-tile; consumes s, updates
// (run_m, run_l, o-rescale), emits the 8 packed-bf16 P words.
static __device__ __forceinline__ void softmax_block(
    const f32x16& s, unsigned mw, float& run_m, float& run_l,
    f32x16 (&o)[5], int h, unsigned (&pw)[8]) {
  float t0 = fmaxf(fmaxf(fmaxf(s[0], s[1]), fmaxf(s[2], s[3])),
                   fmaxf(fmaxf(s[4], s[5]), fmaxf(s[6], s[7])));
  float t1 = fmaxf(fmaxf(fmaxf(s[8], s[9]), fmaxf(s[10], s[11])),
                   fmaxf(fmaxf(s[12], s[13]), fmaxf(s[14], s[15])));
  float pm = fmaxf(t0, t1);
  pm = fmaxf(pm, __shfl_xor(pm, 32));

  // defer-max (T13): skip O-rescale unless max grew by > 8 (log2 units)
  if (!__all(pm - run_m <= 8.0f)) {
    float nm = fmaxf(run_m, pm);
    float f = fexp2(run_m - nm);
    run_m = nm;
    run_l *= f;
#pragma unroll
    for (int dt = 0; dt < 5; dt++) o[dt] *= f;   // rare; unified file handles AGPR
  }

  float rs = 0.0f;
#pragma unroll
  for (int i = 0; i < 8; i++) {
    int k0 = ((2 * i) & 3) + 8 * (i >> 1) + 4 * h;   // key of reg 2i
    float p0 = fexp2(s[2 * i] - run_m);
    float p1 = fexp2(s[2 * i + 1] - run_m);
    p0 = ((mw >> k0) & 1u) ? p0 : 0.0f;              // mask by zeroing P
    p1 = ((mw >> (k0 + 1)) & 1u) ? p1 : 0.0f;
    rs += p0 + p1;
    unsigned w;
    asm("v_cvt_pk_bf16_f32 %0, %1, %2" : "=v"(w) : "v"(p0), "v"(p1));
    pw[i] = w;
  }
  rs += __shfl_xor(rs, 32);
  run_l += rs;
}

// PV accumulate: P-frag assembly via permlane32_swap, then 2x5 AGPR-pinned MFMA.
static __device__ __forceinline__ void pv_block(
    const unsigned (&pw)[8], const bf16x8 (&va)[5], const bf16x8 (&vb_)[5],
    f32x16 (&o)[5]) {
  unsigned a1 = pw[0], b1 = pw[2];
  asm("v_permlane32_swap_b32 %0, %1" : "+v"(a1), "+v"(b1));
  unsigned a2 = pw[1], b2 = pw[3];
  asm("v_permlane32_swap_b32 %0, %1" : "+v"(a2), "+v"(b2));
  union { unsigned w[4]; bf16x8 v; } u;
  u.w[0] = a1; u.w[1] = a2; u.w[2] = b1; u.w[3] = b2;
  __builtin_amdgcn_s_setprio(1);
#pragma unroll
  for (int dt = 0; dt < 5; dt++) mfma_a(o[dt], va[dt], u.v);
  __builtin_amdgcn_s_setprio(0);
  unsigned c1 = pw[4], d1 = pw[6];
  asm("v_permlane32_swap_b32 %0, %1" : "+v"(c1), "+v"(d1));
  unsigned c2 = pw[5], d2 = pw[7];
  asm("v_permlane32_swap_b32 %0, %1" : "+v"(c2), "+v"(d2));
  union { unsigned w[4]; bf16x8 v; } u2;
  u2.w[0] = c1; u2.w[1] = c2; u2.w[2] = d1; u2.w[3] = d2;
  __builtin_amdgcn_s_setprio(1);
#pragma unroll
  for (int dt = 0; dt < 5; dt++) mfma_a(o[dt], vb_[dt], u2.v);
  __builtin_amdgcn_s_setprio(0);
}

// ---------------- fused masked flash attention v11 ----------------
// attn10 (verified) + AGPR-pinned O accumulators: 64 q-rows per wave, the
// same 20.5 KB/iter of K/V feeds 40 MFMA -> loop read traffic and load-instr
// count per unit work both halve, with ZERO spill (o0/o1 = 160 AGPRs; arch
// VGPR demand ~210 < 256). 576 one-wave blocks, no barriers in the loop.
__global__ __launch_bounds__(64, 1) void attn11_kernel(
    const char* __restrict__ qfrag, const char* __restrict__ kfrag,
    const char* __restrict__ vfrag, const unsigned int* __restrict__ bitsF,
    float* __restrict__ out) {
  __shared__ __align__(16) char smem[20480];   // epilogue transpose (per tile)
  const int lane = threadIdx.x & 63;
  const int l31 = lane & 31, h = lane >> 5;
  const int lane16 = lane * 16;
  const int id = blockIdx.x;
  const int rem = (id & 7) * 72 + (id >> 3);   // XCD-chunked remap (576 = 8*72)
  const int bh = rem / 36, qq = rem - (rem / 36) * 36;
  const int b = bh >> 3;
  const int qt0 = qq * 2;                      // two consecutive 32-row q-tiles

  const char* qfb0 = qfrag + (size_t)bh * FRAG_BH + (size_t)qt0 * KCH_STR;
  const char* kfb = kfrag + (size_t)bh * FRAG_BH;
  const char* vfb = vfrag + (size_t)bh * FRAG_BH;
  const unsigned int* bb0 = bitsF + (size_t)(b * 72 + qt0) * 72 * 32 + l31;
  const unsigned int* bb1 = bb0 + 72 * 32;

  // Q fragments for both tiles (pre-scaled by SCALE*LOG2E)
  bf16x8 qf0[10], qf1[10];
#pragma unroll
  for (int ks = 0; ks < 10; ks++) {
    qf0[ks] = *(const bf16x8*)(qfb0 + ks * 1024 + lane16);
    qf1[ks] = *(const bf16x8*)(qfb0 + KCH_STR + ks * 1024 + lane16);
  }

  const f32x16 zz = {0.f,0.f,0.f,0.f,0.f,0.f,0.f,0.f,0.f,0.f,0.f,0.f,0.f,0.f,0.f,0.f};
  f32x16 o0[5], o1[5];
#pragma unroll
  for (int dt = 0; dt < 5; dt++) { o0[dt] = zz; o1[dt] = zz; }
  float m0 = -3.0e38f, l0 = 0.0f, m1 = -3.0e38f, l1 = 0.0f;

  bf16x8 kf[10];
#pragma unroll
  for (int ks = 0; ks < 10; ks++) kf[ks] = *(const bf16x8*)(kfb + ks * 1024 + lane16);

  for (int kt = 0; kt < 72; kt++) {
    unsigned mw0 = bb0[kt * 32];
    unsigned mw1 = bb1[kt * 32];

    // V fragments for this tile: issued first (cover = 2x QK^T + softmax0)
    const char* vch = vfb + (size_t)kt * KCH_STR;
    bf16x8 va[5], vb_[5];
#pragma unroll
    for (int dt = 0; dt < 5; dt++) va[dt] = *(const bf16x8*)(vch + dt * 1024 + lane16);
#pragma unroll
    for (int dt = 0; dt < 5; dt++)
      vb_[dt] = *(const bf16x8*)(vch + 5120 + dt * 1024 + lane16);

    // S^T for both q-tiles (independent chains, shared kf)
    f32x16 s0 = zz, s1 = zz;
    __builtin_amdgcn_s_setprio(1);
#pragma unroll
    for (int ks = 0; ks < 10; ks++) s0 = MFMA32(kf[ks], qf0[ks], s0);
#pragma unroll
    for (int ks = 0; ks < 10; ks++) s1 = MFMA32(kf[ks], qf1[ks], s1);
    __builtin_amdgcn_s_setprio(0);

    // prefetch next K tile (after both QK^T consumed kf; cover = softmax+PV)
    if (kt + 1 < 72) {
      const char* kr = kfb + (size_t)(kt + 1) * KCH_STR;
#pragma unroll
      for (int ks = 0; ks < 10; ks++) kf[ks] = *(const bf16x8*)(kr + ks * 1024 + lane16);
    }

    unsigned pw0[8], pw1[8];
    softmax_block(s0, mw0, m0, l0, o0, h, pw0);
    pv_block(pw0, va, vb_, o0);                 // softmax1 VALU overlaps these MFMAs
    softmax_block(s1, mw1, m1, l1, o1, h, pw1);
    pv_block(pw1, va, vb_, o1);
  }

  // ---- epilogue: two tiles sequentially through the 20KB LDS transpose ----
  auto store_tile = [&](const f32x16 (&o)[5], float run_l, int q0v) {
    float invl = 1.0f / run_l;
#pragma unroll
    for (int dt = 0; dt < 5; dt++)
#pragma unroll
      for (int rr = 0; rr < 4; rr++) {
        float4 t;
        t.x = o[dt][4 * rr + 0] * invl;
        t.y = o[dt][4 * rr + 1] * invl;
        t.z = o[dt][4 * rr + 2] * invl;
        t.w = o[dt][4 * rr + 3] * invl;
        int d0 = dt * 32 + 8 * rr + 4 * h;
        *(float4*)(smem + l31 * 640 + ((d0 * 4) ^ ((l31 & 7) << 4))) = t;
      }
    __syncthreads();
    float* outp = out + ((size_t)b * N_TOK + q0v) * CDIM + (bh & 7) * DH;
#pragma unroll
    for (int i = 0; i < 20; i++) {
      int c = i * 64 + lane;
      int q = c / 40, f = c - (c / 40) * 40;
      float4 t = *(const float4*)(smem + q * 640 + ((f * 16) ^ ((q & 7) << 4)));
      *(float4*)&outp[(size_t)q * CDIM + f * 4] = t;
    }
    __syncthreads();   // before LDS reuse by the next tile
  };
  store_tile(o0, l0, qt0 * 32);
  store_tile(o1, l1, qt0 * 32 + 32);
}

// ---------------- launcher ----------------
extern "C" void kernel_launch(void* const* d_in, const int* in_sizes, int n_in,
                              void* d_out, int out_size, void* d_ws, size_t ws_size,
                              hipStream_t stream) {
  const float* hs    = (const float*)d_in[0];
  const float* wq    = (const float*)d_in[1];
  const float* wk    = (const float*)d_in[2];
  const float* wvw   = (const float*)d_in[3];
  const float* masks = (const float*)d_in[4];
  float* out = (float*)d_out;

  char* ws = (char*)d_ws;
  unsigned short* xbf = (unsigned short*)(ws);                    // 11,796,480 B
  unsigned short* wt  = (unsigned short*)(ws + 11796480);         //  9,830,400 B
  char* qf = ws + 21626880;                                       // 11,796,480 B
  char* kf = ws + 33423360;                                       // 11,796,480 B
  char* vf = ws + 45219840;                                       // 11,796,480 B
  unsigned int* bitsF = (unsigned int*)(ws + 57016320);           //  1,327,104 B
  // total workspace: 58,343,424 B

  prep_fused_kernel<<<49152, 256, 0, stream>>>(hs, wq, wk, wvw, masks, xbf, wt, bitsF);
  gemm_qkv_kernel<<<dim3(36, 30), 256, 0, stream>>>(xbf, wt, qf, kf, vf);
  attn11_kernel<<<576, 64, 0, stream>>>(qf, kf, vf, bitsF, out);
}

// Round 13
// 189.010 us; speedup vs baseline: 1.7572x; 1.7239x over previous
//
#include <hip/hip_runtime.h>

// Problem constants
#define N_TOK 2304
#define CDIM  1280
#define NH    8
#define DH    160
#define NKT   36          // N_TOK / 64  (u64 bitmask words per row)
#define SCALE 0.07905694150420949f   // 1/sqrt(160)
#define LOG2E 1.4426950408889634f

// Fragment-major buffer geometry (bytes)
#define FRAG_BH   737280     // 160*2304*2 per (b,h)
#define KCH_STR   10240      // 10 ks-chunks of 1KB per 32-key (or 32-q) tile
#define VCH_STR   5120       // 5 dt-chunks of 1KB per 16-key step

typedef __attribute__((ext_vector_type(8))) short bf16x8;
typedef __attribute__((ext_vector_type(4))) float f32x4;
typedef __attribute__((ext_vector_type(16))) float f32x16;

#define MFMA16(a, b, c) __builtin_amdgcn_mfma_f32_16x16x32_bf16((a), (b), (c), 0, 0, 0)
#define MFMA32(a, b, c) __builtin_amdgcn_mfma_f32_32x32x16_bf16((a), (b), (c), 0, 0, 0)

static __device__ __forceinline__ unsigned short f2bf(float f) {
  // round-to-nearest-even f32 -> bf16 (finite inputs only)
  unsigned int u = __builtin_bit_cast(unsigned int, f);
  u += 0x7fffu + ((u >> 16) & 1u);
  return (unsigned short)(u >> 16);
}

static __device__ __forceinline__ float fexp2(float x) {
#if __has_builtin(__builtin_amdgcn_exp2f)
  return __builtin_amdgcn_exp2f(x);
#else
  return exp2f(x);
#endif
}

// global -> LDS direct DMA, 16B per lane. LDS dest = wave-uniform base + lane*16.
static __device__ __forceinline__ void gload_lds16(const void* g, void* l) {
  const __attribute__((address_space(1))) unsigned int* gp =
      (const __attribute__((address_space(1))) unsigned int*)(unsigned long long)(uintptr_t)g;
  __attribute__((address_space(3))) unsigned int* lp =
      (__attribute__((address_space(3))) unsigned int*)(unsigned int)(uintptr_t)l;
  __builtin_amdgcn_global_load_lds(gp, lp, 16, 0, 0);
}

// ---------------- fused prep kernel ----------------
// Section A [0,2880): cast hidden_states f32 -> bf16 (8 elems/thread)
// Section B [2880,7680): Wt[w][n][k] = W_w[k][n] f32 -> bf16 (32x32 LDS tiles)
// Section C [7680,49152): masks -> fragment-blocked visibility bits
__global__ void prep_fused_kernel(const float* __restrict__ x,
                                  const float* __restrict__ wq,
                                  const float* __restrict__ wk,
                                  const float* __restrict__ wv,
                                  const float* __restrict__ masks,
                                  unsigned short* __restrict__ xbf,
                                  unsigned short* __restrict__ wt,
                                  unsigned int* __restrict__ bitsF) {
  const int blk = blockIdx.x;
  const int tid = threadIdx.x;
  if (blk < 2880) {
    int i = blk * 256 + tid;
    const float4* p = (const float4*)x + (size_t)i * 2;
    float4 a = p[0], b = p[1];
    union { unsigned short u[8]; uint4 v; } pk;
    pk.u[0] = f2bf(a.x); pk.u[1] = f2bf(a.y); pk.u[2] = f2bf(a.z); pk.u[3] = f2bf(a.w);
    pk.u[4] = f2bf(b.x); pk.u[5] = f2bf(b.y); pk.u[6] = f2bf(b.z); pk.u[7] = f2bf(b.w);
    ((uint4*)xbf)[i] = pk.v;
  } else if (blk < 7680) {
    __shared__ float t[32][33];
    int idx = blk - 2880;
    int w = idx / 1600, r = idx - w * 1600;
    const float* src = (w == 0) ? wq : ((w == 1) ? wk : wv);
    int bx = (r % 40) * 32, by = (r / 40) * 32;
    int tx = tid & 31, ty = tid >> 5;     // 32 x 8
#pragma unroll
    for (int i = 0; i < 32; i += 8)
      t[ty + i][tx] = src[(size_t)(by + ty + i) * CDIM + bx + tx];
    __syncthreads();
#pragma unroll
    for (int i = 0; i < 32; i += 8)
      wt[((size_t)w * CDIM + bx + ty + i) * CDIM + by + tx] = f2bf(t[tx][ty + i]);
  } else {
    int tt = (blk - 7680) * 256 + tid;
    int word = tt >> 6, lane = tt & 63;
    int jblk = word % NKT, bi = word / NKT;          // bi = b*N + i
    float m = masks[(size_t)bi * N_TOK + jblk * 64 + lane];
    unsigned long long vis = __ballot(m > -5000.0f);
    int b = bi / N_TOK, i = bi - b * N_TOK;
    int qt = i >> 5, ql = i & 31;
    unsigned base = ((unsigned)(b * 72 + qt) * 72 + 2 * jblk) * 32 + ql;
    if (lane == 0)      bitsF[base]      = (unsigned)vis;
    else if (lane == 1) bitsF[base + 32] = (unsigned)(vis >> 32);
  }
}

// ---------------- QKV projection GEMM (unchanged, verified) ----------------
__global__ __launch_bounds__(256, 3) void gemm_qkv_kernel(
    const unsigned short* __restrict__ xbf, const unsigned short* __restrict__ wt,
    char* __restrict__ qfrag, char* __restrict__ kfrag, char* __restrict__ vfrag) {
  __shared__ unsigned short Al[128][64];   // 128B rows, linear (DMA dest)
  __shared__ unsigned short Bl[128][64];
  const int tid = threadIdx.x;
  const int lane = tid & 63, wv = tid >> 6;
  const int wm = wv >> 1, wn = wv & 1;
  const int l15 = lane & 15, l4 = lane >> 4;
  const int m0 = blockIdx.x * 128, n0 = blockIdx.y * 128;
  const int lr8 = lane >> 3;                       // 0..7: row within 8-row slab
  const int scb = ((lane & 7) * 16) ^ (lr8 << 4);  // pre-swizzled source column
  f32x4 zero = {0.f, 0.f, 0.f, 0.f};
  f32x4 acc[4][4];
#pragma unroll
  for (int mt = 0; mt < 4; mt++)
#pragma unroll
    for (int nt = 0; nt < 4; nt++) acc[mt][nt] = zero;

  for (int kk = 0; kk < CDIM; kk += 64) {
    __syncthreads();   // prior reads done before DMA overwrites
    {
      const char* asrc = (const char*)&xbf[(size_t)(m0 + wv * 32) * CDIM + kk];
      const char* bsrc = (const char*)&wt [(size_t)(n0 + wv * 32) * CDIM + kk];
#pragma unroll
      for (int i = 0; i < 4; i++) {
        gload_lds16(asrc + (size_t)(i * 8 + lr8) * (CDIM * 2) + scb, &Al[wv * 32 + i * 8][0]);
        gload_lds16(bsrc + (size_t)(i * 8 + lr8) * (CDIM * 2) + scb, &Bl[wv * 32 + i * 8][0]);
      }
    }
    __syncthreads();   // vmcnt(0) drain emitted before barrier
#pragma unroll
    for (int ks = 0; ks < 2; ks++) {
      bf16x8 af[4], bfr[4];
#pragma unroll
      for (int mt = 0; mt < 4; mt++) {
        int rA = wm * 64 + mt * 16 + l15;
        af[mt] = *(const bf16x8*)((const char*)Al + rA * 128 +
                                  ((ks * 64 + l4 * 16) ^ ((rA & 7) << 4)));
      }
#pragma unroll
      for (int nt = 0; nt < 4; nt++) {
        int rB = wn * 64 + nt * 16 + l15;
        bfr[nt] = *(const bf16x8*)((const char*)Bl + rB * 128 +
                                   ((ks * 64 + l4 * 16) ^ ((rB & 7) << 4)));
      }
#pragma unroll
      for (int mt = 0; mt < 4; mt++)
#pragma unroll
        for (int nt = 0; nt < 4; nt++)
          acc[mt][nt] = MFMA16(af[mt], bfr[nt], acc[mt][nt]);
    }
  }

  const int w_idx = n0 / CDIM;                 // 0=Q 1=K 2=V, block-uniform
  if (w_idx == 0) {
    const float qsc = (float)(0.07905694150420949 * 1.4426950408889634);
#pragma unroll
    for (int mt = 0; mt < 4; mt++)
#pragma unroll
      for (int nt = 0; nt < 4; nt++) acc[mt][nt] *= qsc;
  }
  const int cbase = n0 - w_idx * CDIM + wn * 64;
#pragma unroll
  for (int mt = 0; mt < 4; mt++) {
    const int mg = m0 + wm * 64 + mt * 16 + l4 * 4;  // token row (r=0)
    const int b = mg / N_TOK;
    const int tok = mg - b * N_TOK;
#pragma unroll
    for (int nt = 0; nt < 4; nt++) {
      const int cw = cbase + nt * 16 + l15;
      const int h = cw / DH, d = cw - h * DH;
      const size_t bh = (size_t)(b * NH + h);
      if (w_idx == 2) {
        union { unsigned short u[4]; unsigned long long v; } pk;
        pk.u[0] = f2bf(acc[mt][nt][0]); pk.u[1] = f2bf(acc[mt][nt][1]);
        pk.u[2] = f2bf(acc[mt][nt][2]); pk.u[3] = f2bf(acc[mt][nt][3]);
        char* p = vfrag + bh * FRAG_BH + (tok >> 4) * VCH_STR + (d >> 5) * 1024
                  + ((d & 31) + 32 * ((tok >> 3) & 1)) * 16 + (tok & 7) * 2;
        *(unsigned long long*)p = pk.v;
      } else {
        char* base = (w_idx == 0 ? qfrag : kfrag) + bh * FRAG_BH + (d >> 4) * 1024
                     + ((d >> 3) & 1) * 512 + (d & 7) * 2;
#pragma unroll
        for (int r = 0; r < 4; r++) {
          int t2 = tok + r;
          *(unsigned short*)(base + (t2 >> 5) * KCH_STR + (t2 & 31) * 16) =
              f2bf(acc[mt][nt][r]);
        }
      }
    }
  }
}

// ---------------- fused masked flash attention v12 ----------------
// attn8's verified 1-wave loop, launched as 2-wave blocks where BOTH waves
// traverse the SAME K/V stream (wave w owns q-tile 2*qq+w, same kt order).
// Trailing wave's loads hit the CU's 32KB L1 (stream is 20.5KB/iter) ->
// L2 read traffic halves with zero barriers, zero extra registers.
// 576 blocks x 128 thr = 1152 waves (full SIMD coverage, as attn8).
__global__ __launch_bounds__(128, 2) void attn12_kernel(
    const char* __restrict__ qfrag, const char* __restrict__ kfrag,
    const char* __restrict__ vfrag, const unsigned int* __restrict__ bitsF,
    float* __restrict__ out) {
  __shared__ __align__(16) char smem[40960];   // per-wave 20KB epilogue region
  const int tid = threadIdx.x;
  const int lane = tid & 63, wv = tid >> 6;
  const int l31 = lane & 31, h = lane >> 5;
  const int lane16 = lane * 16;
  const int id = blockIdx.x;
  const int rem = (id & 7) * 72 + (id >> 3);   // XCD-chunked remap (576 = 8*72)
  const int bh = rem / 36, qq = rem - (rem / 36) * 36;
  const int b = bh >> 3;
  const int qt = qq * 2 + wv;                  // this wave's q-tile
  const int q0 = qt * 32;

  const char* qfb = qfrag + (size_t)bh * FRAG_BH + (size_t)qt * KCH_STR;
  const char* kfb = kfrag + (size_t)bh * FRAG_BH;
  const char* vfb = vfrag + (size_t)bh * FRAG_BH;
  const unsigned int* bb = bitsF + (size_t)(b * 72 + qt) * 72 * 32 + l31;

  // Q fragments (pre-scaled by SCALE*LOG2E): lane-coalesced chunk reads
  bf16x8 qf[10];
#pragma unroll
  for (int ks = 0; ks < 10; ks++) qf[ks] = *(const bf16x8*)(qfb + ks * 1024 + lane16);

  const f32x16 zz = {0.f,0.f,0.f,0.f,0.f,0.f,0.f,0.f,0.f,0.f,0.f,0.f,0.f,0.f,0.f,0.f};
  f32x16 o[5];
#pragma unroll
  for (int dt = 0; dt < 5; dt++) o[dt] = zz;
  float run_m = -3.0e38f, run_l = 0.0f;

  bf16x8 kf[10];
#pragma unroll
  for (int ks = 0; ks < 10; ks++) kf[ks] = *(const bf16x8*)(kfb + ks * 1024 + lane16);

  for (int kt = 0; kt < 72; kt++) {
    unsigned mw = bb[kt * 32];

    // V fragments for THIS tile: issued before QK^T -> cover = QK^T + softmax
    const char* vch = vfb + (size_t)kt * KCH_STR;   // 2 V-chunks per 32-key tile
    bf16x8 va[5], vb_[5];
#pragma unroll
    for (int dt = 0; dt < 5; dt++) va[dt] = *(const bf16x8*)(vch + dt * 1024 + lane16);
#pragma unroll
    for (int dt = 0; dt < 5; dt++)
      vb_[dt] = *(const bf16x8*)(vch + 5120 + dt * 1024 + lane16);

    // S^T[key][q] = K . Q^T : lane holds 16 keys of this tile for q = q0+l31
    f32x16 s = zz;
    __builtin_amdgcn_s_setprio(1);
#pragma unroll
    for (int ks = 0; ks < 10; ks++) s = MFMA32(kf[ks], qf[ks], s);
    __builtin_amdgcn_s_setprio(0);

    // prefetch next K tile (after QK^T consumed kf; cover = softmax + PV)
    if (kt + 1 < 72) {
      const char* kr = kfb + (size_t)(kt + 1) * KCH_STR;
#pragma unroll
      for (int ks = 0; ks < 10; ks++) kf[ks] = *(const bf16x8*)(kr + ks * 1024 + lane16);
    }

    // row max: pairwise tree (depth 4) then cross-half swap
    float t0 = fmaxf(fmaxf(fmaxf(s[0], s[1]), fmaxf(s[2], s[3])),
                     fmaxf(fmaxf(s[4], s[5]), fmaxf(s[6], s[7])));
    float t1 = fmaxf(fmaxf(fmaxf(s[8], s[9]), fmaxf(s[10], s[11])),
                     fmaxf(fmaxf(s[12], s[13]), fmaxf(s[14], s[15])));
    float pm = fmaxf(t0, t1);
    pm = fmaxf(pm, __shfl_xor(pm, 32));

    // defer-max (T13): skip O-rescale unless max grew by > 8 (log2 units)
    if (!__all(pm - run_m <= 8.0f)) {
      float nm = fmaxf(run_m, pm);
      float f = fexp2(run_m - nm);
      run_m = nm;
      run_l *= f;
#pragma unroll
      for (int dt = 0; dt < 5; dt++) o[dt] *= f;
    }

    float rs = 0.0f;
    unsigned pw[8];
#pragma unroll
    for (int i = 0; i < 8; i++) {
      int k0 = ((2 * i) & 3) + 8 * (i >> 1) + 4 * h;   // key of reg 2i
      float p0 = fexp2(s[2 * i] - run_m);
      float p1 = fexp2(s[2 * i + 1] - run_m);
      p0 = ((mw >> k0) & 1u) ? p0 : 0.0f;              // mask by zeroing P
      p1 = ((mw >> (k0 + 1)) & 1u) ? p1 : 0.0f;
      rs += p0 + p1;
      unsigned w;
      asm("v_cvt_pk_bf16_f32 %0, %1, %2" : "=v"(w) : "v"(p0), "v"(p1));
      pw[i] = w;
    }
    rs += __shfl_xor(rs, 32);
    run_l += rs;

    // P-frag assembly: swap(pw[0],pw[2])->(w0,w2), swap(pw[1],pw[3])->(w1,w3)
    {
      unsigned a1 = pw[0], b1 = pw[2];
      asm("v_permlane32_swap_b32 %0, %1" : "+v"(a1), "+v"(b1));
      unsigned a2 = pw[1], b2 = pw[3];
      asm("v_permlane32_swap_b32 %0, %1" : "+v"(a2), "+v"(b2));
      union { unsigned w[4]; bf16x8 v; } u;
      u.w[0] = a1; u.w[1] = a2; u.w[2] = b1; u.w[3] = b2;
      __builtin_amdgcn_s_setprio(1);
#pragma unroll
      for (int dt = 0; dt < 5; dt++) o[dt] = MFMA32(va[dt], u.v, o[dt]);
      __builtin_amdgcn_s_setprio(0);
      unsigned c1 = pw[4], d1 = pw[6];
      asm("v_permlane32_swap_b32 %0, %1" : "+v"(c1), "+v"(d1));
      unsigned c2 = pw[5], d2 = pw[7];
      asm("v_permlane32_swap_b32 %0, %1" : "+v"(c2), "+v"(d2));
      union { unsigned w[4]; bf16x8 v; } u2;
      u2.w[0] = c1; u2.w[1] = c2; u2.w[2] = d1; u2.w[3] = d2;
      __builtin_amdgcn_s_setprio(1);
#pragma unroll
      for (int dt = 0; dt < 5; dt++) o[dt] = MFMA32(vb_[dt], u2.v, o[dt]);
      __builtin_amdgcn_s_setprio(0);
    }
  }

  // ---- epilogue: normalize, per-wave LDS transpose region, coalesced store ----
  char* ob = smem + wv * 20480;
  float invl = 1.0f / run_l;
#pragma unroll
  for (int dt = 0; dt < 5; dt++)
#pragma unroll
    for (int rr = 0; rr < 4; rr++) {
      float4 t;
      t.x = o[dt][4 * rr + 0] * invl;
      t.y = o[dt][4 * rr + 1] * invl;
      t.z = o[dt][4 * rr + 2] * invl;
      t.w = o[dt][4 * rr + 3] * invl;
      int d0 = dt * 32 + 8 * rr + 4 * h;
      *(float4*)(ob + l31 * 640 + ((d0 * 4) ^ ((l31 & 7) << 4))) = t;
    }
  __syncthreads();
  // coalesced store: 32 rows x 40 float4, 20 per lane (own q-tile)
  float* outp = out + ((size_t)b * N_TOK + q0) * CDIM + (bh & 7) * DH;
#pragma unroll
  for (int i = 0; i < 20; i++) {
    int c = i * 64 + lane;
    int q = c / 40, f = c - (c / 40) * 40;
    float4 t = *(const float4*)(ob + q * 640 + ((f * 16) ^ ((q & 7) << 4)));
    *(float4*)&outp[(size_t)q * CDIM + f * 4] = t;
  }
}

// ---------------- launcher ----------------
extern "C" void kernel_launch(void* const* d_in, const int* in_sizes, int n_in,
                              void* d_out, int out_size, void* d_ws, size_t ws_size,
                              hipStream_t stream) {
  const float* hs    = (const float*)d_in[0];
  const float* wq    = (const float*)d_in[1];
  const float* wk    = (const float*)d_in[2];
  const float* wvw   = (const float*)d_in[3];
  const float* masks = (const float*)d_in[4];
  float* out = (float*)d_out;

  char* ws = (char*)d_ws;
  unsigned short* xbf = (unsigned short*)(ws);                    // 11,796,480 B
  unsigned short* wt  = (unsigned short*)(ws + 11796480);         //  9,830,400 B
  char* qf = ws + 21626880;                                       // 11,796,480 B
  char* kf = ws + 33423360;                                       // 11,796,480 B
  char* vf = ws + 45219840;                                       // 11,796,480 B
  unsigned int* bitsF = (unsigned int*)(ws + 57016320);           //  1,327,104 B
  // total workspace: 58,343,424 B

  prep_fused_kernel<<<49152, 256, 0, stream>>>(hs, wq, wk, wvw, masks, xbf, wt, bitsF);
  gemm_qkv_kernel<<<dim3(36, 30), 256, 0, stream>>>(xbf, wt, qf, kf, vf);
  attn12_kernel<<<576, 128, 0, stream>>>(qf, kf, vf, bitsF, out);
}